// Round 7
// baseline (476.974 us; speedup 1.0000x reference)
//
#include <hip/hip_runtime.h>
#include <cstdint>
#include <cstddef>
#include <math.h>

#define SEQ 4096
#define DH 2048
#define DOUT 1024

typedef float f32x4 __attribute__((ext_vector_type(4)));
typedef __bf16 bf16x8 __attribute__((ext_vector_type(8)));

// ---- helpers --------------------------------------------------------------

__device__ __forceinline__ unsigned short f2bf(float f) {
  // round-to-nearest-even fp32 -> bf16 (inputs are finite; no NaN handling)
  unsigned int u = __float_as_uint(f);
  unsigned int r = (u + 0x7FFFu + ((u >> 16) & 1u)) >> 16;
  return (unsigned short)r;
}

__device__ __forceinline__ void g2l16(const unsigned short* g, unsigned short* l) {
  // async global -> LDS, 16 bytes per lane. LDS side is wave-uniform base + lane*16.
  __builtin_amdgcn_global_load_lds((__attribute__((address_space(1))) void*)(void*)g,
                                   (__attribute__((address_space(3))) void*)l, 16, 0, 0);
}

// ---- fused prep kernel ----------------------------------------------------
// One launch, three roles by block range (cuts 4 kernel-node boundaries to 1):
//   [0,64):     LN stats + normalize + scale + transpose -> gateT[d][n] bf16
//               (one block per 64-row slab; stats in LDS, x re-read L2-hot)
//   [64,592):   tril-masked cast w fp32->bf16, lower-triangle 128x128 tiles
//   [592,1104): transpose+cast proj_w -> projT[j][d] bf16 (64x64 tiles)

__global__ __launch_bounds__(256) void prep_fused(const float* __restrict__ x,
                                                  const float* __restrict__ lns,
                                                  const float* __restrict__ w,
                                                  const float* __restrict__ pw,
                                                  unsigned short* __restrict__ gateT,
                                                  unsigned short* __restrict__ wb,
                                                  unsigned short* __restrict__ pT) {
  __shared__ float tile[64][65];
  __shared__ float smv[64], srv[64];
  const int tid = threadIdx.x;
  const int bid = blockIdx.x;

  if (bid < 64) {
    // ---- role 1: LN + transpose for rows [n0, n0+64) ----
    const int n0 = bid * 64;
    const int wv = tid >> 6, lane = tid & 63;
    // stats: wave wv handles rows wv*16 .. wv*16+15, fully coalesced
    for (int i = 0; i < 16; i++) {
      int r = wv * 16 + i;
      const float4* base = (const float4*)(x + (size_t)(n0 + r) * (2 * DH) + DH);
      float s = 0.f, s2 = 0.f;
#pragma unroll
      for (int it = 0; it < 8; it++) {
        float4 v = base[lane + it * 64];
        s  += v.x + v.y + v.z + v.w;
        s2 += v.x * v.x + v.y * v.y + v.z * v.z + v.w * v.w;
      }
#pragma unroll
      for (int o = 32; o > 0; o >>= 1) {
        s  += __shfl_down(s, o);
        s2 += __shfl_down(s2, o);
      }
      if (lane == 0) {
        float mean = s * (1.0f / DH);
        float var  = s2 * (1.0f / DH) - mean * mean;  // ddof=0 = jnp.var
        smv[r] = mean;
        srv[r] = rsqrtf(var + 1e-5f);
      }
    }
    __syncthreads();
    // normalize + transpose, 32 d-tiles of 64
    for (int dt = 0; dt < 32; dt++) {
      int d0 = dt * 64;
#pragma unroll
      for (int i = 0; i < 16; i++) {
        int idx = tid + i * 256;
        int r = idx >> 6, c = idx & 63;
        float v = x[(size_t)(n0 + r) * (2 * DH) + DH + d0 + c];
        tile[r][c] = (v - smv[r]) * srv[r];
      }
      __syncthreads();
#pragma unroll
      for (int i = 0; i < 16; i++) {
        int idx = tid + i * 256;
        int dr = idx >> 6, nc = idx & 63;
        gateT[(size_t)(d0 + dr) * SEQ + n0 + nc] = f2bf(tile[nc][dr] * lns[d0 + dr]);
      }
      __syncthreads();
    }
  } else if (bid < 592) {
    // ---- role 2: tril cast, tile t of the lower triangle ----
    int t = bid - 64;
    int i0 = (int)((sqrtf(8.f * (float)t + 1.f) - 1.f) * 0.5f);
    while ((i0 + 1) * (i0 + 2) / 2 <= t) i0++;
    while (i0 * (i0 + 1) / 2 > t) i0--;
    int j0 = t - i0 * (i0 + 1) / 2;  // j0 <= i0
    const bool interior = (j0 < i0);
    const int rowBase = i0 * 128, colBase = j0 * 128;
#pragma unroll
    for (int rnd = 0; rnd < 8; rnd++) {
      int idx = rnd * 256 + tid;       // 0..2047
      int r = idx >> 4, g = idx & 15;
      int m = rowBase + r, k = colBase + g * 8;
      size_t e = (size_t)m * SEQ + k;
      uint4 o;
      if (interior || k + 7 <= m) {
        const float4* s = (const float4*)(w + e);
        float4 a = s[0], b = s[1];
        o.x = (unsigned)f2bf(a.x) | ((unsigned)f2bf(a.y) << 16);
        o.y = (unsigned)f2bf(a.z) | ((unsigned)f2bf(a.w) << 16);
        o.z = (unsigned)f2bf(b.x) | ((unsigned)f2bf(b.y) << 16);
        o.w = (unsigned)f2bf(b.z) | ((unsigned)f2bf(b.w) << 16);
      } else if (k > m) {
        o.x = o.y = o.z = o.w = 0u;
      } else {
        unsigned short tt[8];
#pragma unroll
        for (int j = 0; j < 8; j++) tt[j] = (k + j <= m) ? f2bf(w[e + j]) : (unsigned short)0;
        o.x = (unsigned)tt[0] | ((unsigned)tt[1] << 16);
        o.y = (unsigned)tt[2] | ((unsigned)tt[3] << 16);
        o.z = (unsigned)tt[4] | ((unsigned)tt[5] << 16);
        o.w = (unsigned)tt[6] | ((unsigned)tt[7] << 16);
      }
      *(uint4*)(wb + e) = o;
    }
  } else {
    // ---- role 3: proj_w transpose, tile (j0, d0) ----
    int t = bid - 592;                    // 0..511
    int j0 = (t & 15) * 64, d0 = (t >> 4) * 64;
#pragma unroll
    for (int i = 0; i < 16; i++) {
      int idx = tid + i * 256;
      int r = idx >> 6, c = idx & 63;
      tile[r][c] = pw[(size_t)(d0 + r) * DOUT + j0 + c];
    }
    __syncthreads();
#pragma unroll
    for (int i = 0; i < 16; i++) {
      int idx = tid + i * 256;
      int jr = idx >> 6, dc = idx & 63;
      pT[(size_t)(j0 + jr) * DH + d0 + dc] = f2bf(tile[dc][jr]);
    }
  }
}

// ---- MFMA GEMM, 128x128 tile, 64x64 wave tiles, BK=64, static dbuf --------
// C = A(MxK) * BT(NxK)^T, bf16 in / fp32 acc. 4 waves 2x2, each wave owns a
// 64x64 subtile (4x4 16x16 acc tiles): 32 FLOP per LDS byte (vs 21 for the
// R6 64x32 wave tile) — this kernel is LDS-traffic-bound at ~64 B/cyc
// effective (R3/R5/R6 walls all match bytes/64), so intensity is the lever.
// Per block-iter: 64 KB LDS reads + 32 KB stage writes for 2.1 MFLOP.
//
// Pipeline (R6-proven): static four-array double buffer, stage(i+1) issued
// before compute(i), barrier drain waits on loads a full compute phase old.
//
// CAUSAL (GEMM1): row-block remap by<16?by:47-by puts rows {p,31-p} on
// co-resident block pairs (id, id+256) -> uniform 66 iters per CU.
// kIters = 2*(row+1), always even (loop unrolled x2 requires even).
// EPI==1: P[m][n] = bf16( xfull[m][n] * (acc + rbias[m]) )
// EPI==2: out[m][n] = acc + cbias[n]
//
// LDS: 128 B rows = 32 banks; XOR-8 chunk swizzle (phys = chunk^(row&7)):
// 0 bank conflicts (verified R3/R5/R6). 64 KB/block -> 2 blocks/CU.

template <bool CAUSAL, int EPI>
__global__ __launch_bounds__(256) void gemm128db(const unsigned short* __restrict__ A,
                                                 const unsigned short* __restrict__ BT,
                                                 const float* __restrict__ xfull,
                                                 const float* __restrict__ rbias,
                                                 unsigned short* __restrict__ Pout,
                                                 const float* __restrict__ cbias,
                                                 float* __restrict__ out,
                                                 int N, int K) {
  constexpr int BK = 64;
  __shared__ unsigned short sA0[128 * BK];  // 16 KB each
  __shared__ unsigned short sA1[128 * BK];
  __shared__ unsigned short sB0[128 * BK];
  __shared__ unsigned short sB1[128 * BK];

  const int tid = threadIdx.x;
  const int lane = tid & 63, wave = tid >> 6;
  const int quad = lane >> 4, l16 = lane & 15;
  const int wm = wave >> 1, wn = wave & 1;
  const int bn0 = blockIdx.x * 128;

  int by = blockIdx.y;
  if (CAUSAL) by = (by < 16) ? by : 47 - by;  // pairs (id,id+256) -> rows {p,31-p}
  const int bm0 = by * 128;
  const int kIters = CAUSAL ? 2 * (by + 1) : (K / BK);  // always even

  // staging: slot idx in [0,1024): row = idx>>3, phys chunk = idx&7,
  // data chunk = (idx&7)^(row&7). A and B share offsets (both 128 rows).
  int sOff[4], sDst[4];
#pragma unroll
  for (int r = 0; r < 4; r++) {
    int idx = r * 256 + tid;
    int row = idx >> 3;
    sOff[r] = row * K + (((idx & 7) ^ (row & 7)) * 8);
    sDst[r] = idx * 8;
  }
  const unsigned short* Ab = A + (size_t)bm0 * K;
  const unsigned short* Bb = BT + (size_t)bn0 * K;

  f32x4 acc[4][4] = {};

  auto stage = [&](int i, unsigned short* dA, unsigned short* dB) {
    int kk = i * BK;
#pragma unroll
    for (int r = 0; r < 4; r++) g2l16(Ab + kk + sOff[r], dA + sDst[r]);
#pragma unroll
    for (int r = 0; r < 4; r++) g2l16(Bb + kk + sOff[r], dB + sDst[r]);
  };

  auto compute = [&](const unsigned short* cA, const unsigned short* cB) {
    bf16x8 af[2][4], bf[2][4];
#pragma unroll
    for (int h = 0; h < 2; h++) {
#pragma unroll
      for (int i = 0; i < 4; i++) {
        int R = wm * 64 + i * 16 + l16;
        af[h][i] = *(const bf16x8*)&cA[R * BK + (((h * 4 + quad) ^ (R & 7)) * 8)];
      }
#pragma unroll
      for (int j = 0; j < 4; j++) {
        int R = wn * 64 + j * 16 + l16;
        bf[h][j] = *(const bf16x8*)&cB[R * BK + (((h * 4 + quad) ^ (R & 7)) * 8)];
      }
    }
#pragma unroll
    for (int h = 0; h < 2; h++)
#pragma unroll
      for (int i = 0; i < 4; i++)
#pragma unroll
        for (int j = 0; j < 4; j++)
          acc[i][j] = __builtin_amdgcn_mfma_f32_16x16x32_bf16(af[h][i], bf[h][j], acc[i][j], 0, 0, 0);
  };

  stage(0, sA0, sB0);
  __syncthreads();
  for (int i = 0; i < kIters; i += 2) {
    stage(i + 1, sA1, sB1);           // i+1 <= kIters-1: always valid
    compute(sA0, sB0);
    __syncthreads();                   // drains stage(i+1): issued 1 compute ago
    if (i + 2 < kIters) stage(i + 2, sA0, sB0);
    compute(sA1, sB1);
    __syncthreads();
  }

  // epilogue — C/D layout: col = lane&15, row = quad*4 + reg (m89-verified)
#pragma unroll
  for (int i = 0; i < 4; i++) {
#pragma unroll
    for (int j = 0; j < 4; j++) {
      int col = bn0 + wn * 64 + j * 16 + l16;
#pragma unroll
      for (int r = 0; r < 4; r++) {
        int row = bm0 + wm * 64 + i * 16 + quad * 4 + r;
        float v = acc[i][j][r];
        if (EPI == 1) {
          float g = v + rbias[row];
          float pv = xfull[(size_t)row * (2 * DH) + col] * g;
          Pout[(size_t)row * N + col] = f2bf(pv);
        } else {
          out[(size_t)row * N + col] = v + cbias[col];
        }
      }
    }
  }
}

// ---- launch ---------------------------------------------------------------

extern "C" void kernel_launch(void* const* d_in, const int* in_sizes, int n_in,
                              void* d_out, int out_size, void* d_ws, size_t ws_size,
                              hipStream_t stream) {
  (void)in_sizes; (void)n_in; (void)out_size; (void)ws_size;
  const float* x   = (const float*)d_in[0];
  const float* lns = (const float*)d_in[1];
  const float* w   = (const float*)d_in[2];
  const float* sb  = (const float*)d_in[3];
  const float* pw  = (const float*)d_in[4];
  const float* pb  = (const float*)d_in[5];
  float* out = (float*)d_out;

  char* p = (char*)d_ws;
  unsigned short* gateT = (unsigned short*)p; p += (size_t)DH * SEQ * 2;    // 16 MB
  unsigned short* wb    = (unsigned short*)p; p += (size_t)SEQ * SEQ * 2;   // 32 MB
  unsigned short* projT = (unsigned short*)p; p += (size_t)DOUT * DH * 2;   //  4 MB
  unsigned short* Pbuf  = (unsigned short*)p; p += (size_t)SEQ * DH * 2;    // 16 MB

  // one prep launch: 64 LN/transpose + 528 tril-cast + 512 proj-transpose
  prep_fused<<<1104, 256, 0, stream>>>(x, lns, w, pw, gateT, wb, projT);

  // GEMM1: gate2 = tril(w) @ gate  (M=4096, N=2048, K=4096)
  // 128x128 tiles, grid (16,32)=512 = 2 blocks/CU, causal row remap.
  gemm128db<true, 1><<<dim3(DH / 128, SEQ / 128), 256, 0, stream>>>(
      wb, gateT, x, sb, Pbuf, nullptr, nullptr, DH, SEQ);
  // GEMM2: out = P @ proj_w + proj_b  (M=4096, N=1024, K=2048)
  // grid (8,32)=256 uniform 32-iter blocks.
  gemm128db<false, 2><<<dim3(DOUT / 128, SEQ / 128), 256, 0, stream>>>(
      Pbuf, projT, nullptr, nullptr, nullptr, pb, out, DOUT, DH);
}